// Round 4
// baseline (266.628 us; speedup 1.0000x reference)
//
#include <hip/hip_runtime.h>
#include <hip/hip_bf16.h>

typedef __bf16 bf16_t;
typedef __bf16 bf16x8 __attribute__((ext_vector_type(8)));
typedef float f32x4 __attribute__((ext_vector_type(4)));

typedef const __attribute__((address_space(3))) bf16_t* lds_cptr;

// ---------------------------------------------------------------------------
// fused fp32 -> bf16 cast for 3 arrays (one launch; memory-bound)
// ---------------------------------------------------------------------------
__global__ __launch_bounds__(256) void cast3_f32_to_bf16(
    const float* __restrict__ a, bf16_t* __restrict__ ao, int na8,
    const float* __restrict__ b, bf16_t* __restrict__ bo, int nb8,
    const float* __restrict__ c, bf16_t* __restrict__ co, int nc8) {
  int i = blockIdx.x * blockDim.x + threadIdx.x;
  const float* in;
  bf16_t* out;
  int j;
  if (i < na8) {
    in = a; out = ao; j = i;
  } else if (i < na8 + nb8) {
    in = b; out = bo; j = i - na8;
  } else if (i < na8 + nb8 + nc8) {
    in = c; out = co; j = i - na8 - nb8;
  } else {
    return;
  }
  const float4* in4 = (const float4*)in;
  float4 f0 = in4[2 * j];
  float4 f1 = in4[2 * j + 1];
  bf16x8 o;
  o[0] = (bf16_t)f0.x; o[1] = (bf16_t)f0.y;
  o[2] = (bf16_t)f0.z; o[3] = (bf16_t)f0.w;
  o[4] = (bf16_t)f1.x; o[5] = (bf16_t)f1.y;
  o[6] = (bf16_t)f1.z; o[7] = (bf16_t)f1.w;
  ((bf16x8*)out)[j] = o;
}

// ---------------------------------------------------------------------------
// async global->LDS, 16B per lane. LDS dest = wave-uniform base + lane*16.
// ---------------------------------------------------------------------------
__device__ __forceinline__ void gload_lds16(const bf16_t* g, bf16_t* l) {
  __builtin_amdgcn_global_load_lds(
      (const __attribute__((address_space(1))) void*)g,
      (__attribute__((address_space(3))) void*)l,
      16, 0, 0);
}

// No "memory" clobber on waitcnt asm (a clobber re-attracts a compiler
// vmcnt(0) DMA drain). Ordering: volatile asm mutual order + sched_barrier.
template <int N>
__device__ __forceinline__ void vmwait() {
  if constexpr (N == 3) asm volatile("s_waitcnt vmcnt(3)");
  else if constexpr (N == 4) asm volatile("s_waitcnt vmcnt(4)");
  else asm volatile("s_waitcnt vmcnt(0)");
}

template <int N>
__device__ __forceinline__ void lgkmwait() {
  asm volatile("s_waitcnt lgkmcnt(%0)" :: "i"(N));
}

// inline-asm ds_read_b128 batch: dst[I] <- LDS[p + (BOFF + I*1024) bytes].
template <int I, int N, int BOFF>
__device__ __forceinline__ void ldsr_n(bf16x8* dst, lds_cptr p) {
  if constexpr (I < N) {
    asm volatile("ds_read_b128 %0, %1 offset:%2"
                 : "=v"(dst[I]) : "v"(p), "i"(BOFF + I * 1024));
    ldsr_n<I + 1, N, BOFF>(dst, p);
  }
}

// MFMA row-groups with counted lgkm waits: reads were issued in order
// B[0..FC-1], A[0..FR-1] (total FR+FC). Group i needs B[*] + A[i], i.e.
// FC+i+1 reads done -> allowed outstanding = FR-1-i. DS reads complete
// in-order per wave, so the count releases exactly the frag needed while
// later reads keep draining UNDER the MFMAs (the overlap this round adds).
// sched_barrier(0) after each wait: rule #18 (MFMA hoists past asm waits).
template <int I, int FR, int FC>
__device__ __forceinline__ void mfma_rows(const bf16x8* aq, const bf16x8* bq,
                                          f32x4 (&acc)[FR][FC]) {
  if constexpr (I < FR) {
    lgkmwait<FR - 1 - I>();
    __builtin_amdgcn_sched_barrier(0);
#pragma unroll
    for (int j = 0; j < FC; ++j)
      acc[I][j] = __builtin_amdgcn_mfma_f32_16x16x32_bf16(
          aq[I], bq[j], acc[I][j], 0, 0, 0);
    mfma_rows<I + 1, FR, FC>(aq, bq, acc);
  }
}

// ---------------------------------------------------------------------------
// Pipelined GEMM: C[M,N] = A[M,K]*B[N,K]^T + bias[N], optional fused swish.
// BM=256 x BN tile, 512 threads (8 waves), 16x16x32 bf16 MFMA.
// K in subtiles of 32, four LDS buffers (buf = s & 3), stage prefetch
// depth 3. ONE phase per subtile (one barrier, one vmcnt):
//   issue FR+FC ds_read_b128 (B then A); issue stage(s+3);
//   FR MFMA groups with counted lgkm waits (reads drain under MFMA);
//   vmcnt(VMN); s_barrier.
// vmcnt(VMN) at end of s: only stage(s+3) (VMN calls, this subtile) may
// remain -> stage(s+2) complete, so reads at s+1/s+2 are safe (cross-wave
// via the barrier). Last MFMA group ends at lgkmcnt(0), so buf s&3 reads
// are drained before the barrier -> stage(s+4) may overwrite it next
// subtile. Tail stages wrap mod NS into dead buffers.
// LDS: [row][32] bf16 rows (64B), 16B chunk swizzle phys = chunk ^
// (((row&15)>>1)&3); staged linearly via pre-swizzled per-lane global src.
// Requires: M%256==0, N%BN==0, K%128==0.
// ---------------------------------------------------------------------------
#define SMALL_TILE(s_, b_)                                                    \
  {                                                                           \
    int sw__ = (s_) + 3;                                                      \
    if (sw__ >= NS) sw__ -= NS;                                               \
    lds_cptr pa3 = sA3 + (b_) * (256 * 32) + aoff;                            \
    lds_cptr pb3 = sB3 + (b_) * (BN * 32) + boff;                             \
    bf16x8 bq[FC], aq[FR];                                                    \
    ldsr_n<0, FC, 0>(bq, pb3);                                                \
    ldsr_n<0, FR, 0>(aq, pa3);                                                \
    stageA(sw__);                                                             \
    stageB(sw__);                                                             \
    __builtin_amdgcn_s_setprio(1);                                            \
    mfma_rows<0, FR, FC>(aq, bq, acc);                                        \
    __builtin_amdgcn_s_setprio(0);                                            \
    vmwait<VMN>();                                                            \
    __builtin_amdgcn_s_barrier();                                             \
  }

template <int BN, int WM, int WN, bool SWISH>
__global__ __launch_bounds__(512, 2) void gemm_bt8(
    const bf16_t* __restrict__ A, const bf16_t* __restrict__ B,
    const float* __restrict__ bias, void* __restrict__ Cout,
    int M, int N, int K, int XW, int px, int py) {
  constexpr int BM = 256;
  constexpr int WR = BM / WM;      // wave rows
  constexpr int WC = BN / WN;      // wave cols
  constexpr int FR = WR / 16;      // frag rows per wave
  constexpr int FC = WC / 16;      // frag cols per wave
  constexpr int ACALLS = BM / 128;       // gload calls per A subtile (2)
  constexpr int BCALLS = BN / 128;       // 2 (BN=256) or 1 (BN=128)
  constexpr int VMN = ACALLS + BCALLS;   // counted-vmcnt allowance

  const int tid = threadIdx.x;
  const int wave = tid >> 6;
  const int lane = tid & 63;

  // ---- XCD-aware block swizzle (grid % 8 == 0 in both uses) ----
  const int bid = blockIdx.x;
  const int xcd = bid & 7;
  const int idx = bid >> 3;
  const int cx = xcd % XW;
  const int cy = xcd / XW;
  const int bx = cx * px + idx % px;
  const int by = cy * py + idx / px;
  const int tileM = by * BM;
  const int tileN = bx * BN;

  __shared__ __align__(16) bf16_t sA[4 * 256 * 32];
  __shared__ __align__(16) bf16_t sB[4 * BN * 32];
  lds_cptr sA3 = (lds_cptr)sA;
  lds_cptr sB3 = (lds_cptr)sB;

  // ---- staging geometry: one call = 512 thr x 16B = 128 rows x 32 cols ----
  // lane -> row lane>>2, phys chunk lane&3 (linear LDS);
  // fetches GLOBAL chunk (lane&3) ^ ((lane>>3)&3)  [= chunk ^ ((row&15)>>1)&3]
  const int srow = (wave << 4) + (lane >> 2);              // 0..127
  const int sgc = ((lane & 3) ^ ((lane >> 3) & 3)) << 3;   // 0..24, global col
  const bf16_t* gA = A + (size_t)(tileM + srow) * K + sgc;
  const bf16_t* gB = B + (size_t)(tileN + srow) * K + sgc;
  bf16_t* lA = sA + (wave << 9);  // wave-uniform LDS base (wave*16 rows)
  bf16_t* lB = sB + (wave << 9);

  auto stageA = [&](int s) {
    bf16_t* l = lA + (s & 3) * (256 * 32);
    const bf16_t* g = gA + s * 32;
#pragma unroll
    for (int c = 0; c < ACALLS; ++c)
      gload_lds16(g + (size_t)(c * 128) * K, l + c * 128 * 32);
  };
  auto stageB = [&](int s) {
    bf16_t* l = lB + (s & 3) * (BN * 32);
    const bf16_t* g = gB + s * 32;
#pragma unroll
    for (int c = 0; c < BCALLS; ++c)
      gload_lds16(g + (size_t)(c * 128) * K, l + c * 128 * 32);
  };

  // ---- fragment read offsets (within one buffer, elements) ----
  const int wr = wave / WN;
  const int wc = wave % WN;
  const int fr = lane & 15;
  const int pc = (lane >> 4) ^ ((fr >> 1) & 3);  // swizzled phys chunk
  const int aoff = (wr * WR + fr) * 32 + pc * 8;
  const int boff = (wc * WC + fr) * 32 + pc * 8;

  f32x4 acc[FR][FC] = {};

  const int NS = K >> 5;  // 32-wide K subtiles; NS % 4 == 0

  // ---- prologue: stage subtiles 0,1,2; force 0,1 complete; sync ----
  stageA(0); stageB(0);
  stageA(1); stageB(1);
  stageA(2); stageB(2);
  vmwait<VMN>();
  __builtin_amdgcn_s_barrier();

  // ---- main loop: 4 subtiles per iteration (static buf index) ----
  for (int os = 0; os < NS; os += 4) {
    SMALL_TILE(os + 0, 0)
    SMALL_TILE(os + 1, 1)
    SMALL_TILE(os + 2, 2)
    SMALL_TILE(os + 3, 3)
  }

  // ---- epilogue: C/D layout col = lane&15, row = (lane>>4)*4 + reg ----
  const int cRow0 = tileM + wr * WR + ((lane >> 4) << 2);
  const int cCol0 = tileN + wc * WC + (lane & 15);
#pragma unroll
  for (int j = 0; j < FC; ++j) {
    const int col = cCol0 + j * 16;
    const float bv = bias[col];
#pragma unroll
    for (int i = 0; i < FR; ++i) {
      const int row = cRow0 + i * 16;
#pragma unroll
      for (int r = 0; r < 4; ++r) {
        float h = acc[i][j][r] + bv;
        if constexpr (SWISH) {
          float h3 = h * h * h;
          float sw = h * (0.5f + 0.25f * h - 0.0208f * h3);
          ((bf16_t*)Cout)[(size_t)(row + r) * N + col] = (bf16_t)sw;
        } else {
          ((float*)Cout)[(size_t)(row + r) * N + col] = h;
        }
      }
    }
  }
}

// ---------------------------------------------------------------------------
// launch
// ---------------------------------------------------------------------------
extern "C" void kernel_launch(void* const* d_in, const int* in_sizes, int n_in,
                              void* d_out, int out_size, void* d_ws,
                              size_t ws_size, hipStream_t stream) {
  const float* X  = (const float*)d_in[0];  // [B,S,D] = [M,D]
  const float* W1 = (const float*)d_in[1];  // [F,D]
  const float* b1 = (const float*)d_in[2];  // [F]
  const float* W2 = (const float*)d_in[3];  // [D,F]
  const float* b2 = (const float*)d_in[4];  // [D]
  float* out = (float*)d_out;               // [M,D]

  const int F = in_sizes[2];      // 4096
  const int D = in_sizes[4];      // 1024
  const int M = in_sizes[0] / D;  // 8192

  // workspace layout (bf16): Xb[M*D] | W1b[F*D] | W2b[D*F] | SW[M*F]
  bf16_t* Xb  = (bf16_t*)d_ws;
  bf16_t* W1b = Xb + (size_t)M * D;
  bf16_t* W2b = W1b + (size_t)F * D;
  bf16_t* SW  = W2b + (size_t)D * F;

  const int nX = (M * D) / 8, nW1 = (F * D) / 8, nW2 = (D * F) / 8;
  const int nTot = nX + nW1 + nW2;
  cast3_f32_to_bf16<<<(nTot + 255) / 256, 256, 0, stream>>>(
      X, Xb, nX, W1, W1b, nW1, W2, W2b, nW2);

  // GEMM1: SW[M,F] = swish(Xb[M,D] @ W1b[F,D]^T + b1)   (bf16 out)
  // 256x256 tiles: gx = F/256 = 16, gy = M/256 = 32; XCDs as 2x4 -> 8x8 patch
  {
    const int gx = F / 256, gy = M / 256;
    const int XW = 2, XH = 4;
    const int px = gx / XW, py = gy / XH;
    gemm_bt8<256, 2, 4, true><<<gx * gy, 512, 0, stream>>>(
        Xb, W1b, b1, (void*)SW, M, F, D, XW, px, py);
  }

  // GEMM2: out[M,D] = SW[M,F] @ W2b[D,F]^T + b2         (fp32 out)
  // 256x128 tiles: gx = D/128 = 8, gy = M/256 = 32; XCDs as 1x8 -> 8x4 patch
  {
    const int gx = D / 128, gy = M / 256;
    const int XW = 1, XH = 8;
    const int px = gx / XW, py = gy / XH;
    gemm_bt8<128, 4, 2, false><<<gx * gy, 512, 0, stream>>>(
        SW, W2b, b2, (void*)out, M, D, F, XW, px, py);
  }
}

// Round 5
// 241.182 us; speedup vs baseline: 1.1055x; 1.1055x over previous
//
#include <hip/hip_runtime.h>
#include <hip/hip_bf16.h>

typedef __bf16 bf16_t;
typedef __bf16 bf16x8 __attribute__((ext_vector_type(8)));
typedef float f32x4 __attribute__((ext_vector_type(4)));

typedef const __attribute__((address_space(3))) bf16_t* lds_cptr;

// ---------------------------------------------------------------------------
// fused fp32 -> bf16 cast for 3 arrays (one launch; memory-bound)
// ---------------------------------------------------------------------------
__global__ __launch_bounds__(256) void cast3_f32_to_bf16(
    const float* __restrict__ a, bf16_t* __restrict__ ao, int na8,
    const float* __restrict__ b, bf16_t* __restrict__ bo, int nb8,
    const float* __restrict__ c, bf16_t* __restrict__ co, int nc8) {
  int i = blockIdx.x * blockDim.x + threadIdx.x;
  const float* in;
  bf16_t* out;
  int j;
  if (i < na8) {
    in = a; out = ao; j = i;
  } else if (i < na8 + nb8) {
    in = b; out = bo; j = i - na8;
  } else if (i < na8 + nb8 + nc8) {
    in = c; out = co; j = i - na8 - nb8;
  } else {
    return;
  }
  const float4* in4 = (const float4*)in;
  float4 f0 = in4[2 * j];
  float4 f1 = in4[2 * j + 1];
  bf16x8 o;
  o[0] = (bf16_t)f0.x; o[1] = (bf16_t)f0.y;
  o[2] = (bf16_t)f0.z; o[3] = (bf16_t)f0.w;
  o[4] = (bf16_t)f1.x; o[5] = (bf16_t)f1.y;
  o[6] = (bf16_t)f1.z; o[7] = (bf16_t)f1.w;
  ((bf16x8*)out)[j] = o;
}

// ---------------------------------------------------------------------------
// async global->LDS, 16B per lane. LDS dest = wave-uniform base + lane*16.
// ---------------------------------------------------------------------------
__device__ __forceinline__ void gload_lds16(const bf16_t* g, bf16_t* l) {
  __builtin_amdgcn_global_load_lds(
      (const __attribute__((address_space(1))) void*)g,
      (__attribute__((address_space(3))) void*)l,
      16, 0, 0);
}

// No "memory" clobber on waitcnt asm (a clobber re-attracts a compiler
// vmcnt(0) DMA drain). Ordering: volatile asm mutual order + sched_barrier.
template <int N>
__device__ __forceinline__ void vmwait() {
  if constexpr (N == 3) asm volatile("s_waitcnt vmcnt(3)");
  else if constexpr (N == 4) asm volatile("s_waitcnt vmcnt(4)");
  else if constexpr (N == 6) asm volatile("s_waitcnt vmcnt(6)");
  else if constexpr (N == 8) asm volatile("s_waitcnt vmcnt(8)");
  else asm volatile("s_waitcnt vmcnt(0)");
}

template <int N>
__device__ __forceinline__ void lgkmwait() {
  asm volatile("s_waitcnt lgkmcnt(%0)" :: "i"(N));
}

// inline-asm ds_read_b128 batch: dst[I] <- LDS[p + (BOFF + I*1024) bytes].
template <int I, int N, int BOFF>
__device__ __forceinline__ void ldsr_n(bf16x8* dst, lds_cptr p) {
  if constexpr (I < N) {
    asm volatile("ds_read_b128 %0, %1 offset:%2"
                 : "=v"(dst[I]) : "v"(p), "i"(BOFF + I * 1024));
    ldsr_n<I + 1, N, BOFF>(dst, p);
  }
}

// MFMA row-groups with counted lgkm waits: reads were issued in order
// B[0..FC-1], A[0..FR-1] (total FR+FC). Group i needs B[*] + A[i], i.e.
// FC+i+1 reads done -> allowed outstanding = FR-1-i. DS reads complete
// in-order per wave, so the count releases exactly the frag needed while
// later reads keep draining UNDER the MFMAs.
// sched_barrier(0) after each wait: rule #18 (MFMA hoists past asm waits).
template <int I, int FR, int FC>
__device__ __forceinline__ void mfma_rows(const bf16x8* aq, const bf16x8* bq,
                                          f32x4 (&acc)[FR][FC]) {
  if constexpr (I < FR) {
    lgkmwait<FR - 1 - I>();
    __builtin_amdgcn_sched_barrier(0);
#pragma unroll
    for (int j = 0; j < FC; ++j)
      acc[I][j] = __builtin_amdgcn_mfma_f32_16x16x32_bf16(
          aq[I], bq[j], acc[I][j], 0, 0, 0);
    mfma_rows<I + 1, FR, FC>(aq, bq, acc);
  }
}

// ---------------------------------------------------------------------------
// Pipelined GEMM: C[M,N] = A[M,K]*B[N,K]^T + bias[N], optional fused swish.
// BM=256 x BN tile, 512 threads (8 waves), 16x16x32 bf16 MFMA.
// K in subtiles of 32, four LDS buffers (buf = s & 3), stage prefetch
// depth 3. ONE phase per subtile (one barrier, one vmcnt):
//   issue FR+FC ds_read_b128 (B then A); issue stage(s+3);
//   FR MFMA groups with counted lgkm waits (reads drain under MFMA);
//   vmcnt(2*VMN); s_barrier.
// DEEP counted vmcnt (this round's change): allowing 2*VMN outstanding
// permits stages (s+2) AND (s+3) to stay in flight; the wait only forces
// stage(s+1) -- issued TWO bodies ago -- to complete. Reads at s+1 need
// exactly stage(s+1): correct, and the DMA now has ~2 body-times of
// latency budget instead of ~1 (the prior schedule equilibrated at body
// time ~= loaded DMA latency ~1900cy; this is the latency-exposure fix).
// Buffer overwrite safety: last MFMA group waits lgkmcnt(0), so all reads
// of buf s&3 are drained before the barrier -> stage(s+4) may overwrite.
// Tail stages wrap mod NS into dead buffers.
// LDS: [row][32] bf16 rows (64B), 16B chunk swizzle phys = chunk ^
// (((row&15)>>1)&3); staged linearly via pre-swizzled per-lane global src.
// Requires: M%256==0, N%BN==0, K%128==0.
// ---------------------------------------------------------------------------
#define SMALL_TILE(s_, b_)                                                    \
  {                                                                           \
    int sw__ = (s_) + 3;                                                      \
    if (sw__ >= NS) sw__ -= NS;                                               \
    lds_cptr pa3 = sA3 + (b_) * (256 * 32) + aoff;                            \
    lds_cptr pb3 = sB3 + (b_) * (BN * 32) + boff;                             \
    bf16x8 bq[FC], aq[FR];                                                    \
    ldsr_n<0, FC, 0>(bq, pb3);                                                \
    ldsr_n<0, FR, 0>(aq, pa3);                                                \
    stageA(sw__);                                                             \
    stageB(sw__);                                                             \
    __builtin_amdgcn_s_setprio(1);                                            \
    mfma_rows<0, FR, FC>(aq, bq, acc);                                        \
    __builtin_amdgcn_s_setprio(0);                                            \
    vmwait<2 * VMN>();                                                        \
    __builtin_amdgcn_s_barrier();                                             \
  }

template <int BN, int WM, int WN, bool SWISH>
__global__ __launch_bounds__(512, 2) void gemm_bt8(
    const bf16_t* __restrict__ A, const bf16_t* __restrict__ B,
    const float* __restrict__ bias, void* __restrict__ Cout,
    int M, int N, int K, int XW, int px, int py) {
  constexpr int BM = 256;
  constexpr int WR = BM / WM;      // wave rows
  constexpr int WC = BN / WN;      // wave cols
  constexpr int FR = WR / 16;      // frag rows per wave
  constexpr int FC = WC / 16;      // frag cols per wave
  constexpr int ACALLS = BM / 128;       // gload calls per A subtile (2)
  constexpr int BCALLS = BN / 128;       // 2 (BN=256) or 1 (BN=128)
  constexpr int VMN = ACALLS + BCALLS;   // gload instrs per subtile stage

  const int tid = threadIdx.x;
  const int wave = tid >> 6;
  const int lane = tid & 63;

  // ---- XCD-aware block swizzle (grid % 8 == 0 in both uses) ----
  const int bid = blockIdx.x;
  const int xcd = bid & 7;
  const int idx = bid >> 3;
  const int cx = xcd % XW;
  const int cy = xcd / XW;
  const int bx = cx * px + idx % px;
  const int by = cy * py + idx / px;
  const int tileM = by * BM;
  const int tileN = bx * BN;

  __shared__ __align__(16) bf16_t sA[4 * 256 * 32];
  __shared__ __align__(16) bf16_t sB[4 * BN * 32];
  lds_cptr sA3 = (lds_cptr)sA;
  lds_cptr sB3 = (lds_cptr)sB;

  // ---- staging geometry: one call = 512 thr x 16B = 128 rows x 32 cols ----
  // lane -> row lane>>2, phys chunk lane&3 (linear LDS);
  // fetches GLOBAL chunk (lane&3) ^ ((lane>>3)&3)  [= chunk ^ ((row&15)>>1)&3]
  const int srow = (wave << 4) + (lane >> 2);              // 0..127
  const int sgc = ((lane & 3) ^ ((lane >> 3) & 3)) << 3;   // 0..24, global col
  const bf16_t* gA = A + (size_t)(tileM + srow) * K + sgc;
  const bf16_t* gB = B + (size_t)(tileN + srow) * K + sgc;
  bf16_t* lA = sA + (wave << 9);  // wave-uniform LDS base (wave*16 rows)
  bf16_t* lB = sB + (wave << 9);

  auto stageA = [&](int s) {
    bf16_t* l = lA + (s & 3) * (256 * 32);
    const bf16_t* g = gA + s * 32;
#pragma unroll
    for (int c = 0; c < ACALLS; ++c)
      gload_lds16(g + (size_t)(c * 128) * K, l + c * 128 * 32);
  };
  auto stageB = [&](int s) {
    bf16_t* l = lB + (s & 3) * (BN * 32);
    const bf16_t* g = gB + s * 32;
#pragma unroll
    for (int c = 0; c < BCALLS; ++c)
      gload_lds16(g + (size_t)(c * 128) * K, l + c * 128 * 32);
  };

  // ---- fragment read offsets (within one buffer, elements) ----
  const int wr = wave / WN;
  const int wc = wave % WN;
  const int fr = lane & 15;
  const int pc = (lane >> 4) ^ ((fr >> 1) & 3);  // swizzled phys chunk
  const int aoff = (wr * WR + fr) * 32 + pc * 8;
  const int boff = (wc * WC + fr) * 32 + pc * 8;

  f32x4 acc[FR][FC] = {};

  const int NS = K >> 5;  // 32-wide K subtiles; NS % 4 == 0

  // ---- prologue: stage subtiles 0,1,2; force 0 complete; sync ----
  stageA(0); stageB(0);
  stageA(1); stageB(1);
  stageA(2); stageB(2);
  vmwait<2 * VMN>();
  __builtin_amdgcn_s_barrier();

  // ---- main loop: 4 subtiles per iteration (static buf index) ----
  for (int os = 0; os < NS; os += 4) {
    SMALL_TILE(os + 0, 0)
    SMALL_TILE(os + 1, 1)
    SMALL_TILE(os + 2, 2)
    SMALL_TILE(os + 3, 3)
  }

  // ---- epilogue: C/D layout col = lane&15, row = (lane>>4)*4 + reg ----
  // j INNERMOST: the 4 stores that fill one 128B line are adjacent in
  // program order so L2 merges them into full sectors (round-4 counters
  // showed 2-2.4x HBM write amplification with j-outer scalar stores).
  const int cRow0 = tileM + wr * WR + ((lane >> 4) << 2);
  const int cCol0 = tileN + wc * WC + (lane & 15);
  float bv[FC];
#pragma unroll
  for (int j = 0; j < FC; ++j) bv[j] = bias[cCol0 + j * 16];
#pragma unroll
  for (int i = 0; i < FR; ++i) {
#pragma unroll
    for (int r = 0; r < 4; ++r) {
      const size_t row = (size_t)(cRow0 + i * 16 + r);
#pragma unroll
      for (int j = 0; j < FC; ++j) {
        float h = acc[i][j][r] + bv[j];
        if constexpr (SWISH) {
          float h3 = h * h * h;
          float sw = h * (0.5f + 0.25f * h - 0.0208f * h3);
          ((bf16_t*)Cout)[row * N + cCol0 + j * 16] = (bf16_t)sw;
        } else {
          ((float*)Cout)[row * N + cCol0 + j * 16] = h;
        }
      }
    }
  }
}

// ---------------------------------------------------------------------------
// launch
// ---------------------------------------------------------------------------
extern "C" void kernel_launch(void* const* d_in, const int* in_sizes, int n_in,
                              void* d_out, int out_size, void* d_ws,
                              size_t ws_size, hipStream_t stream) {
  const float* X  = (const float*)d_in[0];  // [B,S,D] = [M,D]
  const float* W1 = (const float*)d_in[1];  // [F,D]
  const float* b1 = (const float*)d_in[2];  // [F]
  const float* W2 = (const float*)d_in[3];  // [D,F]
  const float* b2 = (const float*)d_in[4];  // [D]
  float* out = (float*)d_out;               // [M,D]

  const int F = in_sizes[2];      // 4096
  const int D = in_sizes[4];      // 1024
  const int M = in_sizes[0] / D;  // 8192

  // workspace layout (bf16): Xb[M*D] | W1b[F*D] | W2b[D*F] | SW[M*F]
  bf16_t* Xb  = (bf16_t*)d_ws;
  bf16_t* W1b = Xb + (size_t)M * D;
  bf16_t* W2b = W1b + (size_t)F * D;
  bf16_t* SW  = W2b + (size_t)D * F;

  const int nX = (M * D) / 8, nW1 = (F * D) / 8, nW2 = (D * F) / 8;
  const int nTot = nX + nW1 + nW2;
  cast3_f32_to_bf16<<<(nTot + 255) / 256, 256, 0, stream>>>(
      X, Xb, nX, W1, W1b, nW1, W2, W2b, nW2);

  // GEMM1: SW[M,F] = swish(Xb[M,D] @ W1b[F,D]^T + b1)   (bf16 out)
  // 256x256 tiles: gx = F/256 = 16, gy = M/256 = 32; XCDs as 2x4 -> 8x8 patch
  {
    const int gx = F / 256, gy = M / 256;
    const int XW = 2, XH = 4;
    const int px = gx / XW, py = gy / XH;
    gemm_bt8<256, 2, 4, true><<<gx * gy, 512, 0, stream>>>(
        Xb, W1b, b1, (void*)SW, M, F, D, XW, px, py);
  }

  // GEMM2: out[M,D] = SW[M,F] @ W2b[D,F]^T + b2         (fp32 out)
  // 256x128 tiles: gx = D/128 = 8, gy = M/256 = 32; XCDs as 1x8 -> 8x4 patch
  {
    const int gx = D / 128, gy = M / 256;
    const int XW = 1, XH = 8;
    const int px = gx / XW, py = gy / XH;
    gemm_bt8<128, 4, 2, false><<<gx * gy, 512, 0, stream>>>(
        SW, W2b, b2, (void*)out, M, D, F, XW, px, py);
  }
}